// Round 1
// baseline (57.746 us; speedup 1.0000x reference)
//
#include <hip/hip_runtime.h>

namespace {
constexpr int H = 2048, W = 2048;
constexpr int CELLS = H * W;
constexpr int FRAME_ELEMS = 800 * 800 * 3;          // 1,920,000
constexpr int NEWPOS_OFF = FRAME_ELEMS;             // newpos starts here
constexpr int ENERGY_OFF = FRAME_ELEMS + CELLS * 2; // last element
constexpr int RED_BLOCKS = 2048;
constexpr int RED_THREADS = 256;
}

// Compute pos and diff = (newpos_raw - pos) for cell (i,j), replicating the
// reference's f32 op order exactly (no FMA contraction on inexact pairs).
__device__ __forceinline__ void cell_diff(const float2* __restrict__ pos,
                                          const float2* __restrict__ prev,
                                          int i, int j,
                                          float& p0, float& p1,
                                          float& d0, float& d1) {
    const int idx = i * W + j;
    const float2 p = pos[idx];
    p0 = p.x; p1 = p.y;
    float f0 = -9.8f;   // gravity on channel 0
    float f1 = 0.0f;
    // DIRS order: (0,1), (1,0), (0,-1), (-1,0).  f = -(a-b)*4 ; *4 and neg are exact.
    if (j < W - 1) {
        float2 nb = pos[idx + 1];
        f0 = __fadd_rn(f0, __fmul_rn(__fsub_rn(p.x, nb.x), -4.0f));
        f1 = __fadd_rn(f1, __fmul_rn(__fsub_rn(p.y, nb.y), -4.0f));
    }
    if (i < H - 1) {
        float2 nb = pos[idx + W];
        f0 = __fadd_rn(f0, __fmul_rn(__fsub_rn(p.x, nb.x), -4.0f));
        f1 = __fadd_rn(f1, __fmul_rn(__fsub_rn(p.y, nb.y), -4.0f));
    }
    if (j >= 1) {
        float2 nb = pos[idx - 1];
        f0 = __fadd_rn(f0, __fmul_rn(__fsub_rn(p.x, nb.x), -4.0f));
        f1 = __fadd_rn(f1, __fmul_rn(__fsub_rn(p.y, nb.y), -4.0f));
    }
    if (i >= 1) {
        float2 nb = pos[idx - W];
        f0 = __fadd_rn(f0, __fmul_rn(__fsub_rn(p.x, nb.x), -4.0f));
        f1 = __fadd_rn(f1, __fmul_rn(__fsub_rn(p.y, nb.y), -4.0f));
    }
    // pinned points: force[-1, 0:1024:9] = 0 ; force[0, 0:2048:9] = 0 (both channels)
    const bool pin = ((i == H - 1) && (j < W / 2) && (j % 9 == 0)) ||
                     ((i == 0) && (j % 9 == 0));
    if (pin) { f0 = 0.0f; f1 = 0.0f; }
    const float2 pv = prev[idx];
    // newraw = (2*pos - prev) + force   (2*pos exact)
    const float nr0 = __fadd_rn(__fsub_rn(__fmul_rn(2.0f, p.x), pv.x), f0);
    const float nr1 = __fadd_rn(__fsub_rn(__fmul_rn(2.0f, p.y), pv.y), f1);
    d0 = __fsub_rn(nr0, p.x);
    d1 = __fsub_rn(nr1, p.y);
}

__global__ void k_zero_frame(float4* __restrict__ frame4) {
    int idx = blockIdx.x * 256 + threadIdx.x;   // 1875*256 == FRAME_ELEMS/4 exactly
    frame4[idx] = make_float4(0.f, 0.f, 0.f, 0.f);
}

__global__ void k_energy_partial(const float2* __restrict__ pos,
                                 const float2* __restrict__ prev,
                                 double* __restrict__ partials) {
    __shared__ double sm[RED_THREADS];
    const int tid = threadIdx.x;
    double acc = 0.0;
    for (int c = blockIdx.x * RED_THREADS + tid; c < CELLS; c += RED_BLOCKS * RED_THREADS) {
        const int i = c >> 11, j = c & (W - 1);
        float p0, p1, d0, d1;
        cell_diff(pos, prev, i, j, p0, p1, d0, d1);
        const float s = __fadd_rn(__fmul_rn(d0, d0), __fmul_rn(d1, d1));
        const float v = __fsqrt_rn(s);
        acc += (double)__fmul_rn(v, v);   // sum of round(vnorm^2) terms, f64 accum
    }
    sm[tid] = acc;
    __syncthreads();
    for (int s = RED_THREADS / 2; s > 0; s >>= 1) {
        if (tid < s) sm[tid] += sm[tid + s];
        __syncthreads();
    }
    if (tid == 0) partials[blockIdx.x] = sm[0];
}

__global__ void k_finalize(const double* __restrict__ partials,
                           const float* __restrict__ energy_l_in,
                           float* __restrict__ scale_out,
                           float* __restrict__ out_energy) {
    __shared__ double sm[256];
    const int tid = threadIdx.x;
    double acc = 0.0;
    for (int k = tid; k < RED_BLOCKS; k += 256) acc += partials[k];  // fixed order
    sm[tid] = acc;
    __syncthreads();
    for (int s = 128; s > 0; s >>= 1) {
        if (tid < s) sm[tid] += sm[tid + s];
        __syncthreads();
    }
    if (tid == 0) {
        const float energy = (float)sm[0];
        const float el = energy_l_in[0];
        float en = __fmul_rn(fminf(energy, el), 0.99997f);               // min * DECAY
        en = __fadd_rn(__fmul_rn(en, 0.8f), __fmul_rn(energy, 0.2f));    // *pp + *(1-pp)
        const float scale = __fdiv_rn(en, __fadd_rn(energy, 1e-6f));
        const float new_el = __fadd_rn(__fmul_rn(el, 0.997f), __fmul_rn(en, 0.003f));
        scale_out[0] = scale;
        out_energy[0] = new_el;
    }
}

__global__ void k_emit(const float2* __restrict__ pos,
                       const float2* __restrict__ prev,
                       const float* __restrict__ scale_p,
                       float* __restrict__ frame,
                       float2* __restrict__ newpos) {
    const int c = blockIdx.x * 256 + threadIdx.x;
    if (c >= CELLS) return;
    const float scale = scale_p[0];
    const int i = c >> 11, j = c & (W - 1);
    float p0, p1, d0, d1;
    cell_diff(pos, prev, i, j, p0, p1, d0, d1);
    const float s = __fadd_rn(__fmul_rn(d0, d0), __fmul_rn(d1, d1));
    const float v = __fsqrt_rn(s);
    const float vel = __fmul_rn(v, scale);
    const float den = fmaxf(v, 1e-12f);
    const float i0 = __fdiv_rn(d0, den);
    const float i1 = __fdiv_rn(d1, den);
    const float n0 = __fadd_rn(p0, __fmul_rn(i0, vel));
    const float n1 = __fadd_rn(p1, __fmul_rn(i1, vel));
    newpos[c] = make_float2(n0, n1);
    // x = n1/2048*784+10 ; y = n0/2048*104+690  (/2048 == *2^-11, exact)
    const float x = __fadd_rn(__fmul_rn(__fmul_rn(n1, 4.8828125e-4f), 784.0f), 10.0f);
    const float y = __fadd_rn(__fmul_rn(__fmul_rn(n0, 4.8828125e-4f), 104.0f), 690.0f);
    const int xi = (int)fminf(fmaxf(x, 0.0f), 803.0f);
    const int yi = (int)fminf(fmaxf(y, 0.0f), 803.0f);
    const int px = xi - 2, py = yi - 2;   // crop [2:802,2:802]
    if ((unsigned)px < 800u && (unsigned)py < 800u)
        frame[(py * 800 + px) * 3 + 1] = 255.0f;   // green; R,B stay 0 from zeroing
}

extern "C" void kernel_launch(void* const* d_in, const int* in_sizes, int n_in,
                              void* d_out, int out_size, void* d_ws, size_t ws_size,
                              hipStream_t stream) {
    const float2* pos  = (const float2*)d_in[0];
    const float2* prev = (const float2*)d_in[1];
    const float*  el   = (const float*)d_in[2];
    float* out = (float*)d_out;
    double* partials = (double*)d_ws;
    float*  scale_p  = (float*)((char*)d_ws + RED_BLOCKS * sizeof(double));

    hipLaunchKernelGGL(k_zero_frame, dim3(FRAME_ELEMS / 4 / 256), dim3(256), 0, stream,
                       (float4*)out);
    hipLaunchKernelGGL(k_energy_partial, dim3(RED_BLOCKS), dim3(RED_THREADS), 0, stream,
                       pos, prev, partials);
    hipLaunchKernelGGL(k_finalize, dim3(1), dim3(256), 0, stream,
                       partials, el, scale_p, out + ENERGY_OFF);
    hipLaunchKernelGGL(k_emit, dim3(CELLS / 256), dim3(256), 0, stream,
                       pos, prev, scale_p, out, (float2*)(out + NEWPOS_OFF));
}